// Round 1
// baseline (185.795 us; speedup 1.0000x reference)
//
#include <hip/hip_runtime.h>
#include <math.h>

#if __has_builtin(__builtin_amdgcn_exp2f)
#define EXP2F(x) __builtin_amdgcn_exp2f(x)
#else
#define EXP2F(x) exp2f(x)
#endif

namespace {
constexpr int IMG  = 1024;   // H == W == 1024
constexpr int TW   = 64;     // output tile width  (16 threads x 4 px)
constexpr int TH   = 16;     // output tile height (16 threads x 1 row)
constexpr int LDSW = 72;     // 68 used cols (TW+4), padded to 72 -> 288B row stride (16B-aligned)
constexpr int LDSH = TH + 4; // 20 rows
constexpr float BIG   = 1e18f;              // OOB sentinel: forces w == 0 exactly
constexpr float LOG2E = 1.4426950408889634f;
}

__global__ __launch_bounds__(256)
void bilateral5x5(const float* __restrict__ x,
                  const float* __restrict__ p_sx,
                  const float* __restrict__ p_sy,
                  const float* __restrict__ p_sr,
                  float* __restrict__ out)
{
    __shared__ float tile[LDSH * LDSW];

    const int tx  = threadIdx.x;          // 0..15
    const int ty  = threadIdx.y;          // 0..15
    const int tid = ty * 16 + tx;         // 0..255

    const int gx0 = blockIdx.x * TW - 2;  // global x of LDS col 0
    const int gy0 = blockIdx.y * TH - 2;  // global y of LDS row 0
    const float* img = x + (size_t)blockIdx.z * (IMG * IMG);

    // ---- stage (TH+4) x (TW+4) region into LDS, sentinel-filling OOB ----
    for (int idx = tid; idx < LDSH * 68; idx += 256) {
        const int r  = idx / 68;          // compiler -> magic multiply
        const int c  = idx - r * 68;
        const int gx = gx0 + c;
        const int gy = gy0 + r;
        float v = BIG;
        if ((unsigned)gx < (unsigned)IMG && (unsigned)gy < (unsigned)IMG)
            v = img[gy * IMG + gx];
        tile[r * LDSW + c] = v;
    }
    __syncthreads();

    // ---- per-thread uniform constants ----
    const float sxv = p_sx[0], syv = p_sy[0], srv = p_sr[0];
    const float negc2 = -LOG2E / (2.0f * srv * srv);  // exp2 color coefficient
    const float ax    = -LOG2E / (2.0f * sxv * sxv);
    const float ay    = -LOG2E / (2.0f * syv * syv);
    float lsx[5], lsy[5];                 // log2 of spatial weights (no exp needed)
    #pragma unroll
    for (int j = 0; j < 5; ++j) {
        const float dj = (float)((j - 2) * (j - 2));
        lsx[j] = ax * dj;
        lsy[j] = ay * dj;
    }

    // ---- compute: 4 consecutive x-pixels per thread ----
    const int base = tx * 4;              // LDS col of leftmost needed halo (16B-aligned)
    float num[4] = {0.f, 0.f, 0.f, 0.f};
    float den[4] = {0.f, 0.f, 0.f, 0.f};
    float ctr[4];
    {
        const float4 a = *reinterpret_cast<const float4*>(&tile[(ty + 2) * LDSW + base]);
        const float4 b = *reinterpret_cast<const float4*>(&tile[(ty + 2) * LDSW + base + 4]);
        ctr[0] = a.z; ctr[1] = a.w; ctr[2] = b.x; ctr[3] = b.y;
    }

    #pragma unroll
    for (int dy = 0; dy < 5; ++dy) {
        const float4 a = *reinterpret_cast<const float4*>(&tile[(ty + dy) * LDSW + base]);
        const float4 b = *reinterpret_cast<const float4*>(&tile[(ty + dy) * LDSW + base + 4]);
        const float v[8] = {a.x, a.y, a.z, a.w, b.x, b.y, b.z, b.w};
        #pragma unroll
        for (int dx = 0; dx < 5; ++dx) {
            const float ls = lsy[dy] + lsx[dx];
            #pragma unroll
            for (int i = 0; i < 4; ++i) {
                const float xs = v[i + dx];
                const float d  = ctr[i] - xs;
                const float w  = EXP2F(fmaf(d * d, negc2, ls));
                num[i] = fmaf(w, xs, num[i]);
                den[i] += w;
            }
        }
    }

    float* outimg = out + (size_t)blockIdx.z * (IMG * IMG);
    const int oy = blockIdx.y * TH + ty;
    const int ox = blockIdx.x * TW + tx * 4;
    float4 o;
    o.x = num[0] / den[0];
    o.y = num[1] / den[1];
    o.z = num[2] / den[2];
    o.w = num[3] / den[3];
    *reinterpret_cast<float4*>(&outimg[oy * IMG + ox]) = o;
}

extern "C" void kernel_launch(void* const* d_in, const int* in_sizes, int n_in,
                              void* d_out, int out_size, void* d_ws, size_t ws_size,
                              hipStream_t stream) {
    const float* x  = (const float*)d_in[0];
    const float* sx = (const float*)d_in[1];
    const float* sy = (const float*)d_in[2];
    // d_in[3] = sigma_z: dz == 0 always -> term is exactly 0, unused
    const float* sr = (const float*)d_in[4];
    float* out = (float*)d_out;

    const int B = in_sizes[0] / (IMG * IMG);   // 16
    dim3 grid(IMG / TW, IMG / TH, B);          // (16, 64, 16)
    dim3 block(16, 16, 1);
    bilateral5x5<<<grid, block, 0, stream>>>(x, sx, sy, sr, out);
}

// Round 2
// 180.093 us; speedup vs baseline: 1.0317x; 1.0317x over previous
//
#include <hip/hip_runtime.h>
#include <math.h>

#if __has_builtin(__builtin_amdgcn_exp2f)
#define EXP2F(x) __builtin_amdgcn_exp2f(x)
#else
#define EXP2F(x) exp2f(x)
#endif
#if __has_builtin(__builtin_amdgcn_rcpf)
#define RCPF(x) __builtin_amdgcn_rcpf(x)
#else
#define RCPF(x) (1.0f / (x))
#endif

namespace {
constexpr int IMG  = 1024;   // H == W == 1024
constexpr int TW   = 64;     // output tile width  (16 threads x 4 px)
constexpr int TH   = 16;     // output tile height (16 threads x 1 row)
constexpr int LDSW = 72;     // 68 used cols (TW+4), padded to 72 -> 288B row stride (16B-aligned)
constexpr int LDSH = TH + 4; // 20 rows
constexpr float BIG   = 1e18f;              // OOB sentinel: forces w == 0 exactly
constexpr float LOG2E = 1.4426950408889634f;
// s = sqrt(LOG2E/2)/sigma_r ; inv_s = sigma_r * sqrt(2*ln2)
constexpr float K1     = 0.84932180028801907f;  // sqrt(LOG2E/2)
constexpr float INV_K1 = 1.17741002251547466f;  // 1/K1 = sqrt(2*ln2)
}

__global__ __launch_bounds__(256)
void bilateral5x5(const float* __restrict__ x,
                  const float* __restrict__ p_sx,
                  const float* __restrict__ p_sy,
                  const float* __restrict__ p_sr,
                  float* __restrict__ out)
{
    __shared__ float tile[LDSH * LDSW];

    const int tx  = threadIdx.x;          // 0..15
    const int ty  = threadIdx.y;          // 0..15
    const int tid = ty * 16 + tx;         // 0..255

    const int gx0 = blockIdx.x * TW - 2;  // global x of LDS col 0
    const int gy0 = blockIdx.y * TH - 2;  // global y of LDS row 0
    const float* img = x + (size_t)blockIdx.z * (IMG * IMG);

    // color-space pre-scale: u = x * s so per-tap arg = ls - (uc-us)^2 (one fused fma)
    const float srv   = p_sr[0];
    const float s     = K1 / srv;
    const float inv_s = srv * INV_K1;

    // ---- stage (TH+4) x (TW+4) region into LDS (pre-scaled), sentinel-filling OOB ----
    for (int idx = tid; idx < LDSH * 68; idx += 256) {
        const int r  = idx / 68;
        const int c  = idx - r * 68;
        const int gx = gx0 + c;
        const int gy = gy0 + r;
        float v = BIG;                    // unscaled sentinel is still huge -> w == 0
        if ((unsigned)gx < (unsigned)IMG && (unsigned)gy < (unsigned)IMG)
            v = img[gy * IMG + gx] * s;
        tile[r * LDSW + c] = v;
    }
    __syncthreads();

    // ---- per-thread uniform constants (spatial log2-weights: no exp needed) ----
    const float sxv = p_sx[0], syv = p_sy[0];
    const float ax  = -LOG2E / (2.0f * sxv * sxv);
    const float ay  = -LOG2E / (2.0f * syv * syv);
    float lsx[5], lsy[5];
    #pragma unroll
    for (int j = 0; j < 5; ++j) {
        const float dj = (float)((j - 2) * (j - 2));
        lsx[j] = ax * dj;
        lsy[j] = ay * dj;
    }

    // ---- compute: 4 consecutive x-pixels per thread (scaled space) ----
    const int base = tx * 4;              // 16B-aligned LDS col
    float num[4] = {0.f, 0.f, 0.f, 0.f};
    float den[4] = {0.f, 0.f, 0.f, 0.f};
    float ctr[4];
    {
        const float4 a = *reinterpret_cast<const float4*>(&tile[(ty + 2) * LDSW + base]);
        const float4 b = *reinterpret_cast<const float4*>(&tile[(ty + 2) * LDSW + base + 4]);
        ctr[0] = a.z; ctr[1] = a.w; ctr[2] = b.x; ctr[3] = b.y;
    }

    #pragma unroll
    for (int dy = 0; dy < 5; ++dy) {
        const float4 a = *reinterpret_cast<const float4*>(&tile[(ty + dy) * LDSW + base]);
        const float4 b = *reinterpret_cast<const float4*>(&tile[(ty + dy) * LDSW + base + 4]);
        const float v[8] = {a.x, a.y, a.z, a.w, b.x, b.y, b.z, b.w};
        #pragma unroll
        for (int dx = 0; dx < 5; ++dx) {
            const float ls = lsy[dy] + lsx[dx];
            #pragma unroll
            for (int i = 0; i < 4; ++i) {
                const float us = v[i + dx];
                const float d  = ctr[i] - us;                 // v_sub
                const float w  = EXP2F(fmaf(-d, d, ls));      // v_fma (neg mod) + v_exp
                num[i] = fmaf(w, us, num[i]);                 // v_fmac
                den[i] += w;                                  // v_add
            }
        }
    }

    float* outimg = out + (size_t)blockIdx.z * (IMG * IMG);
    const int oy = blockIdx.y * TH + ty;
    const int ox = blockIdx.x * TW + tx * 4;
    float4 o;
    o.x = num[0] * RCPF(den[0]) * inv_s;
    o.y = num[1] * RCPF(den[1]) * inv_s;
    o.z = num[2] * RCPF(den[2]) * inv_s;
    o.w = num[3] * RCPF(den[3]) * inv_s;
    *reinterpret_cast<float4*>(&outimg[oy * IMG + ox]) = o;
}

extern "C" void kernel_launch(void* const* d_in, const int* in_sizes, int n_in,
                              void* d_out, int out_size, void* d_ws, size_t ws_size,
                              hipStream_t stream) {
    const float* x  = (const float*)d_in[0];
    const float* sx = (const float*)d_in[1];
    const float* sy = (const float*)d_in[2];
    // d_in[3] = sigma_z: dz == 0 always -> term is exactly 0, unused
    const float* sr = (const float*)d_in[4];
    float* out = (float*)d_out;

    const int B = in_sizes[0] / (IMG * IMG);   // 16
    dim3 grid(IMG / TW, IMG / TH, B);          // (16, 64, 16)
    dim3 block(16, 16, 1);
    bilateral5x5<<<grid, block, 0, stream>>>(x, sx, sy, sr, out);
}